// Round 11
// baseline (614.347 us; speedup 1.0000x reference)
//
#include <hip/hip_runtime.h>
#include <hip/hip_bf16.h>
#include <math.h>

// Problem: input (16,1024,512) f32, codebook (8192,512) f32
#define N_ROWS 16384
#define DIM    512
#define VOCAB  8192

typedef __attribute__((ext_vector_type(8))) short short8;
typedef __attribute__((ext_vector_type(4))) float f32x4;

__device__ inline unsigned short f2bf(float f) {      // RNE f32 -> bf16 bits
    unsigned u = __float_as_uint(f);
    u += 0x7fff + ((u >> 16) & 1);
    return (unsigned short)(u >> 16);
}

__device__ inline void gload16(const void* g, void* l) {
    __builtin_amdgcn_global_load_lds(
        (const __attribute__((address_space(1))) void*)g,
        (__attribute__((address_space(3))) void*)l, 16, 0, 0);
}

__device__ inline void top2_ins(float s, int v, float& s1, int& i1, float& s2, int& i2) {
    if (s < s1 || (s == s1 && v < i1)) { s2 = s1; i2 = i1; s1 = s; i1 = v; }
    else if (s < s2 || (s == s2 && v < i2)) { s2 = s; i2 = v; }
}

// ---------------------------------------------------------------------------
// fp32 -> bf16 for input x
// ---------------------------------------------------------------------------
__global__ void k_split_hi(const float* __restrict__ in, unsigned short* __restrict__ hi,
                           int n4) {
    int t = blockIdx.x * 256 + threadIdx.x;
    if (t >= n4) return;
    float4 v = reinterpret_cast<const float4*>(in)[t];
    ushort4 h;
    h.x = f2bf(v.x); h.y = f2bf(v.y); h.z = f2bf(v.z); h.w = f2bf(v.w);
    reinterpret_cast<ushort4*>(hi)[t] = h;
}

// ---------------------------------------------------------------------------
// codebook: fp32 -> bf16 AND c2[v] = sum(cb[v]^2) in one pass (validated)
// ---------------------------------------------------------------------------
__global__ void k_split_cb(const float* __restrict__ cb, unsigned short* __restrict__ hi,
                           float* __restrict__ c2) {
    int row  = blockIdx.x * 4 + (threadIdx.x >> 6);
    int lane = threadIdx.x & 63;
    const float4* p = reinterpret_cast<const float4*>(cb + (size_t)row * DIM);
    float4 a = p[lane * 2], b = p[lane * 2 + 1];
    float s = a.x*a.x + a.y*a.y + a.z*a.z + a.w*a.w
            + b.x*b.x + b.y*b.y + b.z*b.z + b.w*b.w;
    short8 h;
    h[0] = f2bf(a.x); h[1] = f2bf(a.y); h[2] = f2bf(a.z); h[3] = f2bf(a.w);
    h[4] = f2bf(b.x); h[5] = f2bf(b.y); h[6] = f2bf(b.z); h[7] = f2bf(b.w);
    *reinterpret_cast<short8*>(hi + (size_t)row * DIM + lane * 8) = h;
#pragma unroll
    for (int off = 32; off > 0; off >>= 1) s += __shfl_xor(s, off, 64);
    if (lane == 0) c2[row] = s;
}

// ---------------------------------------------------------------------------
// bf16 MFMA GEMM (K=512) + fused per-tile top-2 argmin.
// EXACT r2/r4-validated skeleton (128x128 tile, BK=64, 256 thr, single-buffer
// LDS + __syncthreads staging, rule-21 XOR swizzle, 2.6 blocks/CU) with ONE
// parameter change: wave tiling 32x128 -> 64x64 (2M x 2N), cutting the
// dominant per-step ds_read count 20 -> 16 (same 64-reg acc, no spill risk).
// Epilogue: per-wave 64-col top-2 -> LDS scr merge (r9/r10-validated) ->
// per-128-col part layout identical to r2..r10 (k_select unchanged).
// ---------------------------------------------------------------------------
__launch_bounds__(256, 2)
__global__ void k_mfma_argmin(const unsigned short* __restrict__ xhi,
                              const unsigned short* __restrict__ cbhi,
                              const float* __restrict__ c2,
                              float4* __restrict__ part) {
    __shared__ __align__(16) char As[16384];   // [128 rows][64 bf16], swizzled
    __shared__ __align__(16) char Bs[16384];
    const int tid  = threadIdx.x;
    const int w    = tid >> 6;
    const int lane = tid & 63;
    const int l15  = lane & 15;
    const int lg   = lane >> 4;
    const int wm   = w >> 1, wn = w & 1;   // 2M x 2N wave grid, 64x64 per wave
    const int rowBase = blockIdx.y * 128;
    const int colBase = blockIdx.x * 128;

    f32x4 acc[4][4];
#pragma unroll
    for (int mi = 0; mi < 4; ++mi)
#pragma unroll
        for (int nj = 0; nj < 4; ++nj) acc[mi][nj] = (f32x4)0.f;

    // staging (r2/r4-validated, 0 conflicts): chunk = 1024B = 8 rows of 128B;
    // lane -> (r = 8*chunk + lane>>3, slot = lane&7); source slot ^= row&7.
    const int r8     = lane >> 3;
    const int srcoff = ((lane & 7) ^ r8) << 4;

    for (int kt = 0; kt < 8; ++kt) {          // 8 K-tiles of 64 = K 512
        const int kb = kt << 7;               // byte offset within 1024B row
        if (kt) __syncthreads();
#pragma unroll
        for (int t = 0; t < 4; ++t) {
            int i  = 4 * w + t;               // chunk index 0..15
            int r0 = 8 * i;
            gload16((const char*)xhi + (size_t)(rowBase + r0 + r8) * 1024 + kb + srcoff,
                    As + 1024 * i);
            gload16((const char*)cbhi + (size_t)(colBase + r0 + r8) * 1024 + kb + srcoff,
                    Bs + 1024 * i);
        }
        __syncthreads();
#pragma unroll
        for (int kk = 0; kk < 2; ++kk) {
            const int ob = kk * 64 + lg * 16;
            short8 a[4], b[4];
#pragma unroll
            for (int mi = 0; mi < 4; ++mi) {
                int r = wm * 64 + mi * 16 + l15;
                a[mi] = *(const short8*)(As + r * 128 + (ob ^ ((r & 7) << 4)));
            }
#pragma unroll
            for (int nj = 0; nj < 4; ++nj) {
                int r = wn * 64 + nj * 16 + l15;
                b[nj] = *(const short8*)(Bs + r * 128 + (ob ^ ((r & 7) << 4)));
            }
#pragma unroll
            for (int mi = 0; mi < 4; ++mi)
#pragma unroll
                for (int nj = 0; nj < 4; ++nj)
                    acc[mi][nj] = __builtin_amdgcn_mfma_f32_16x16x32_bf16(
                        a[mi], b[nj], acc[mi][nj], 0, 0, 0);
        }
    }

    // Epilogue: score = c2 - 2*acc; per-wave top-2 over its 64 cols, then LDS
    // merge of the wn pair -> per-128-col top-2 (part layout = r2..r10).
    // C frag: col = l15, row = 4*lg + reg.
    float c2v[4];
#pragma unroll
    for (int nj = 0; nj < 4; ++nj) c2v[nj] = c2[colBase + wn * 64 + nj * 16 + l15];

    __syncthreads();              // staging reads done; reuse As as scr
    float4* scr = (float4*)As;    // [128 rows][2 wn], 4 KB
#pragma unroll
    for (int mi = 0; mi < 4; ++mi) {
#pragma unroll
        for (int reg = 0; reg < 4; ++reg) {
            float s1 = INFINITY, s2 = INFINITY;
            int   i1 = 0x7fffffff, i2 = 0x7fffffff;
#pragma unroll
            for (int nj = 0; nj < 4; ++nj) {
                float sc = fmaf(-2.f, acc[mi][nj][reg], c2v[nj]);
                int   v  = colBase + wn * 64 + nj * 16 + l15;
                top2_ins(sc, v, s1, i1, s2, i2);
            }
#pragma unroll
            for (int off = 1; off < 16; off <<= 1) {   // butterfly, 16 col-lanes
                float t1 = __shfl_xor(s1, off, 64); int j1 = __shfl_xor(i1, off, 64);
                float t2 = __shfl_xor(s2, off, 64); int j2 = __shfl_xor(i2, off, 64);
                bool bf = (t1 < s1) || (t1 == s1 && j1 < i1);
                if (bf) {
                    float ns; int ni;
                    if (s1 < t2 || (s1 == t2 && i1 < j2)) { ns = s1; ni = i1; }
                    else                                   { ns = t2; ni = j2; }
                    s1 = t1; i1 = j1; s2 = ns; i2 = ni;
                } else if (t1 < s2 || (t1 == s2 && j1 < i2)) { s2 = t1; i2 = j1; }
            }
            if (l15 == 0)
                scr[(wm * 64 + mi * 16 + 4 * lg + reg) * 2 + wn] =
                    make_float4(s1, __int_as_float(i1), s2, __int_as_float(i2));
        }
    }
    __syncthreads();
    if (tid < 128) {   // one merger per row: combine the 2 wn entries
        float s1 = INFINITY, s2 = INFINITY;
        int   i1 = 0x7fffffff, i2 = 0x7fffffff;
#pragma unroll
        for (int q = 0; q < 2; ++q) {
            float4 p = scr[tid * 2 + q];
            top2_ins(p.x, __float_as_int(p.y), s1, i1, s2, i2);
            top2_ins(p.z, __float_as_int(p.w), s1, i1, s2, i2);
        }
        part[(size_t)(rowBase + tid) * 64 + blockIdx.x] =
            make_float4(s1, __int_as_float(i1), s2, __int_as_float(i2));
    }
}

// ---------------------------------------------------------------------------
// Per-row final: approx global min over 64 per-128-col top2s; exact fp32
// rescore of all candidates within min+1.0 (>14 sigma of bf16 approx error);
// lexicographic (score, idx) min == reference argmin semantics.
// ---------------------------------------------------------------------------
__global__ void k_select(const float4* __restrict__ part,
                         const float* __restrict__ x,
                         const float* __restrict__ cb,
                         const float* __restrict__ c2,
                         float* __restrict__ out_idx_f,
                         int* __restrict__ idx_i,
                         int* __restrict__ used) {
    int wv   = threadIdx.x >> 6;
    int lane = threadIdx.x & 63;
    int row  = blockIdx.x * 4 + wv;
    float4 p = part[(size_t)row * 64 + lane];
    float s1 = p.x; int i1 = __float_as_int(p.y);
    float s2 = p.z; int i2 = __float_as_int(p.w);
    float gm = s1;
#pragma unroll
    for (int off = 1; off < 64; off <<= 1) gm = fminf(gm, __shfl_xor(gm, off, 64));
    float thresh = gm + 1.0f;
    unsigned long long m1 = __ballot(s1 <= thresh);
    unsigned long long m2 = __ballot(s2 <= thresh);
    float be = INFINITY; int bi = 0x7fffffff;
    const float4* xr = reinterpret_cast<const float4*>(x + (size_t)row * DIM);
    while (m1 | m2) {
        int vi;
        if (m1) { int t = __ffsll(m1) - 1; m1 &= m1 - 1; vi = __shfl(i1, t); }
        else    { int t = __ffsll(m2) - 1; m2 &= m2 - 1; vi = __shfl(i2, t); }
        const float4* cr = reinterpret_cast<const float4*>(cb + (size_t)vi * DIM);
        float d = 0.f;
#pragma unroll
        for (int q = 0; q < 2; ++q) {
            float4 a = xr[q * 64 + lane];
            float4 b = cr[q * 64 + lane];
            d += a.x * b.x + a.y * b.y + a.z * b.z + a.w * b.w;
        }
#pragma unroll
        for (int off = 1; off < 64; off <<= 1) d += __shfl_xor(d, off, 64);
        float se = c2[vi] - 2.f * d;
        if (se < be || (se == be && vi < bi)) { be = se; bi = vi; }
    }
    if (lane == 0) {
        out_idx_f[row] = (float)bi;
        idx_i[row]     = bi;
        used[bi]       = 1;
    }
}

__global__ void k_streak(const int* __restrict__ streak_in,
                         const int* __restrict__ used,
                         float* __restrict__ out) {
    int v = blockIdx.x * 256 + threadIdx.x;
    if (v < VOCAB) out[v] = used[v] ? 0.f : (float)(streak_in[v] + 1);
}

__global__ void k_gather(const float* __restrict__ cb,
                         const int* __restrict__ idx_i,
                         float* __restrict__ out) {
    size_t t  = (size_t)blockIdx.x * 256 + threadIdx.x;
    int    n  = (int)(t >> 7);
    int    d4 = (int)(t & 127);
    reinterpret_cast<float4*>(out)[t] =
        reinterpret_cast<const float4*>(cb + (size_t)idx_i[n] * DIM)[d4];
}

extern "C" void kernel_launch(void* const* d_in, const int* in_sizes, int n_in,
                              void* d_out, int out_size, void* d_ws, size_t ws_size,
                              hipStream_t stream) {
    const float* x      = (const float*)d_in[0];
    const float* cb     = (const float*)d_in[1];
    const int*   streak = (const int*)d_in[2];

    float* out       = (float*)d_out;
    float* out_embed = out;
    float* out_idx   = out + (size_t)N_ROWS * DIM;
    float* out_strk  = out_idx + N_ROWS;

    char* ws = (char*)d_ws;
    unsigned short* xhi  = (unsigned short*)(ws);                 // 16.8 MB
    unsigned short* cbhi = (unsigned short*)(ws + (32u << 20));   // 8.4 MB
    float* c2    = (float*)(ws + (48u << 20));                    // 32 KB
    int*   idx_i = (int*)(ws + (48u << 20) + (1u << 16));         // 64 KB
    int*   used  = (int*)(ws + (48u << 20) + (2u << 16));         // 32 KB
    float4* part = (float4*)(ws + (49u << 20));                   // 16.8 MB

    hipMemsetAsync(used, 0, VOCAB * sizeof(int), stream);
    k_split_hi<<<(N_ROWS * DIM / 4) / 256, 256, 0, stream>>>(x, xhi, N_ROWS * DIM / 4);
    k_split_cb<<<VOCAB / 4, 256, 0, stream>>>(cb, cbhi, c2);
    k_mfma_argmin<<<dim3(VOCAB / 128, N_ROWS / 128), 256, 0, stream>>>(
        xhi, cbhi, c2, part);
    k_select<<<N_ROWS / 4, 256, 0, stream>>>(part, x, cb, c2, out_idx, idx_i, used);
    k_streak<<<VOCAB / 256, 256, 0, stream>>>(streak, used, out_strk);
    k_gather<<<(N_ROWS * DIM / 4) / 256, 256, 0, stream>>>(cb, idx_i, out_embed);
}

// Round 12
// 380.067 us; speedup vs baseline: 1.6164x; 1.6164x over previous
//
#include <hip/hip_runtime.h>
#include <hip/hip_bf16.h>
#include <math.h>

// Problem: input (16,1024,512) f32, codebook (8192,512) f32
#define N_ROWS 16384
#define DIM    512
#define VOCAB  8192

typedef __attribute__((ext_vector_type(8))) short short8;
typedef __attribute__((ext_vector_type(4))) float f32x4;

__device__ inline unsigned short f2bf(float f) {      // RNE f32 -> bf16 bits
    unsigned u = __float_as_uint(f);
    u += 0x7fff + ((u >> 16) & 1);
    return (unsigned short)(u >> 16);
}

__device__ inline void gload16(const void* g, void* l) {
    __builtin_amdgcn_global_load_lds(
        (const __attribute__((address_space(1))) void*)g,
        (__attribute__((address_space(3))) void*)l, 16, 0, 0);
}

// ---------------------------------------------------------------------------
// fp32 -> bf16 for input x
// ---------------------------------------------------------------------------
__global__ void k_split_hi(const float* __restrict__ in, unsigned short* __restrict__ hi,
                           int n4) {
    int t = blockIdx.x * 256 + threadIdx.x;
    if (t >= n4) return;
    float4 v = reinterpret_cast<const float4*>(in)[t];
    ushort4 h;
    h.x = f2bf(v.x); h.y = f2bf(v.y); h.z = f2bf(v.z); h.w = f2bf(v.w);
    reinterpret_cast<ushort4*>(hi)[t] = h;
}

// ---------------------------------------------------------------------------
// codebook: fp32 -> bf16 AND c2[v] = sum(cb[v]^2) in one pass (validated)
// ---------------------------------------------------------------------------
__global__ void k_split_cb(const float* __restrict__ cb, unsigned short* __restrict__ hi,
                           float* __restrict__ c2) {
    int row  = blockIdx.x * 4 + (threadIdx.x >> 6);
    int lane = threadIdx.x & 63;
    const float4* p = reinterpret_cast<const float4*>(cb + (size_t)row * DIM);
    float4 a = p[lane * 2], b = p[lane * 2 + 1];
    float s = a.x*a.x + a.y*a.y + a.z*a.z + a.w*a.w
            + b.x*b.x + b.y*b.y + b.z*b.z + b.w*b.w;
    short8 h;
    h[0] = f2bf(a.x); h[1] = f2bf(a.y); h[2] = f2bf(a.z); h[3] = f2bf(a.w);
    h[4] = f2bf(b.x); h[5] = f2bf(b.y); h[6] = f2bf(b.z); h[7] = f2bf(b.w);
    *reinterpret_cast<short8*>(hi + (size_t)row * DIM + lane * 8) = h;
#pragma unroll
    for (int off = 32; off > 0; off >>= 1) s += __shfl_xor(s, off, 64);
    if (lane == 0) c2[row] = s;
}

// ---------------------------------------------------------------------------
// bf16 MFMA GEMM (K=512) + fused per-tile top-2 argmin.
// 256x128 tile (M doubled vs r4 for B-reuse; AI 64 -> 85 FLOP/staged-byte),
// 512 threads = 8 waves, each wave = 32 rows x 128 cols -- the per-wave
// inner loop, frag reads (a[2], b[8] broadcast), XOR swizzle, and direct
// register->part epilogue are BYTE-IDENTICAL to the validated r2/r4 kernel.
// Single-buffer LDS (A 32KB + B 16KB = 48KB -> 3 blocks/CU resident for
// cross-block overlap), __syncthreads-staged, 4096 blocks.
// ---------------------------------------------------------------------------
__launch_bounds__(512, 1)
__global__ void k_mfma_argmin(const unsigned short* __restrict__ xhi,
                              const unsigned short* __restrict__ cbhi,
                              const float* __restrict__ c2,
                              float4* __restrict__ part) {
    __shared__ __align__(16) char As[32768];   // [256 rows][64 bf16], swizzled
    __shared__ __align__(16) char Bs[16384];   // [128 rows][64 bf16], swizzled
    const int tid  = threadIdx.x;
    const int w8   = tid >> 6;                 // 0..7 : wave = 32 rows x 128 cols
    const int lane = tid & 63;
    const int l15  = lane & 15;
    const int lg   = lane >> 4;
    const int rowBase = blockIdx.y * 256;
    const int colBase = blockIdx.x * 128;

    f32x4 acc[2][8];
#pragma unroll
    for (int mi = 0; mi < 2; ++mi)
#pragma unroll
        for (int nj = 0; nj < 8; ++nj) acc[mi][nj] = (f32x4)0.f;

    // staging (r2/r4-validated scheme): chunk = 1024B = 8 rows of 128B;
    // lane -> (r = 8*chunk + lane>>3, slot = lane&7); source slot ^= row&7.
    const int r8     = lane >> 3;
    const int srcoff = ((lane & 7) ^ r8) << 4;

    for (int kt = 0; kt < 8; ++kt) {          // 8 K-tiles of 64 = K 512
        const int kb = kt << 7;               // byte offset within 1024B row
        if (kt) __syncthreads();
#pragma unroll
        for (int t = 0; t < 4; ++t) {         // A: 32 chunks over 8 waves
            int i  = 4 * w8 + t;
            int r0 = 8 * i;
            gload16((const char*)xhi + (size_t)(rowBase + r0 + r8) * 1024 + kb + srcoff,
                    As + 1024 * i);
        }
#pragma unroll
        for (int t = 0; t < 2; ++t) {         // B: 16 chunks over 8 waves
            int i  = 2 * w8 + t;
            int r0 = 8 * i;
            gload16((const char*)cbhi + (size_t)(colBase + r0 + r8) * 1024 + kb + srcoff,
                    Bs + 1024 * i);
        }
        __syncthreads();
#pragma unroll
        for (int kk = 0; kk < 2; ++kk) {
            const int ob = kk * 64 + lg * 16;
            short8 a[2], b[8];
#pragma unroll
            for (int mi = 0; mi < 2; ++mi) {
                int r = w8 * 32 + mi * 16 + l15;
                a[mi] = *(const short8*)(As + r * 128 + (ob ^ ((r & 7) << 4)));
            }
#pragma unroll
            for (int nj = 0; nj < 8; ++nj) {
                int r = nj * 16 + l15;
                b[nj] = *(const short8*)(Bs + r * 128 + (ob ^ ((r & 7) << 4)));
            }
#pragma unroll
            for (int mi = 0; mi < 2; ++mi)
#pragma unroll
                for (int nj = 0; nj < 8; ++nj)
                    acc[mi][nj] = __builtin_amdgcn_mfma_f32_16x16x32_bf16(
                        a[mi], b[nj], acc[mi][nj], 0, 0, 0);
        }
    }

    // Epilogue (r2/r4-validated, direct register write, no LDS merge):
    // score = c2[v] - 2*dot; per-row top-2 over this block's 128 cols.
    // C layout (m89): col = lane&15, row = 4*(lane>>4) + reg.
    float c2v[8];
#pragma unroll
    for (int nj = 0; nj < 8; ++nj) c2v[nj] = c2[colBase + nj * 16 + l15];

#pragma unroll
    for (int mi = 0; mi < 2; ++mi) {
#pragma unroll
        for (int reg = 0; reg < 4; ++reg) {
            float s1 = INFINITY, s2 = INFINITY;
            int   i1 = 0x7fffffff, i2 = 0x7fffffff;
#pragma unroll
            for (int nj = 0; nj < 8; ++nj) {
                float s = fmaf(-2.f, acc[mi][nj][reg], c2v[nj]);
                int   v = colBase + nj * 16 + l15;
                if (s < s1 || (s == s1 && v < i1)) { s2 = s1; i2 = i1; s1 = s; i1 = v; }
                else if (s < s2 || (s == s2 && v < i2)) { s2 = s; i2 = v; }
            }
#pragma unroll
            for (int off = 1; off < 16; off <<= 1) {   // butterfly over 16 col-lanes
                float t1 = __shfl_xor(s1, off, 64); int j1 = __shfl_xor(i1, off, 64);
                float t2 = __shfl_xor(s2, off, 64); int j2 = __shfl_xor(i2, off, 64);
                bool bfirst = (t1 < s1) || (t1 == s1 && j1 < i1);
                if (bfirst) {
                    float n2s; int n2i;
                    if (s1 < t2 || (s1 == t2 && i1 < j2)) { n2s = s1; n2i = i1; }
                    else                                   { n2s = t2; n2i = j2; }
                    s1 = t1; i1 = j1; s2 = n2s; i2 = n2i;
                } else {
                    if (t1 < s2 || (t1 == s2 && j1 < i2)) { s2 = t1; i2 = j1; }
                }
            }
            if (l15 == 0) {
                int row = rowBase + w8 * 32 + mi * 16 + 4 * lg + reg;
                part[(size_t)row * 64 + blockIdx.x] =
                    make_float4(s1, __int_as_float(i1), s2, __int_as_float(i2));
            }
        }
    }
}

// ---------------------------------------------------------------------------
// Per-row final: approx global min over 64 per-128-col top2s; exact fp32
// rescore of all candidates within min+1.0 (>14 sigma of bf16 approx error);
// lexicographic (score, idx) min == reference argmin semantics.
// ---------------------------------------------------------------------------
__global__ void k_select(const float4* __restrict__ part,
                         const float* __restrict__ x,
                         const float* __restrict__ cb,
                         const float* __restrict__ c2,
                         float* __restrict__ out_idx_f,
                         int* __restrict__ idx_i,
                         int* __restrict__ used) {
    int wv   = threadIdx.x >> 6;
    int lane = threadIdx.x & 63;
    int row  = blockIdx.x * 4 + wv;
    float4 p = part[(size_t)row * 64 + lane];
    float s1 = p.x; int i1 = __float_as_int(p.y);
    float s2 = p.z; int i2 = __float_as_int(p.w);
    float gm = s1;
#pragma unroll
    for (int off = 1; off < 64; off <<= 1) gm = fminf(gm, __shfl_xor(gm, off, 64));
    float thresh = gm + 1.0f;
    unsigned long long m1 = __ballot(s1 <= thresh);
    unsigned long long m2 = __ballot(s2 <= thresh);
    float be = INFINITY; int bi = 0x7fffffff;
    const float4* xr = reinterpret_cast<const float4*>(x + (size_t)row * DIM);
    while (m1 | m2) {
        int vi;
        if (m1) { int t = __ffsll(m1) - 1; m1 &= m1 - 1; vi = __shfl(i1, t); }
        else    { int t = __ffsll(m2) - 1; m2 &= m2 - 1; vi = __shfl(i2, t); }
        const float4* cr = reinterpret_cast<const float4*>(cb + (size_t)vi * DIM);
        float d = 0.f;
#pragma unroll
        for (int q = 0; q < 2; ++q) {
            float4 a = xr[q * 64 + lane];
            float4 b = cr[q * 64 + lane];
            d += a.x * b.x + a.y * b.y + a.z * b.z + a.w * b.w;
        }
#pragma unroll
        for (int off = 1; off < 64; off <<= 1) d += __shfl_xor(d, off, 64);
        float se = c2[vi] - 2.f * d;
        if (se < be || (se == be && vi < bi)) { be = se; bi = vi; }
    }
    if (lane == 0) {
        out_idx_f[row] = (float)bi;
        idx_i[row]     = bi;
        used[bi]       = 1;
    }
}

__global__ void k_streak(const int* __restrict__ streak_in,
                         const int* __restrict__ used,
                         float* __restrict__ out) {
    int v = blockIdx.x * 256 + threadIdx.x;
    if (v < VOCAB) out[v] = used[v] ? 0.f : (float)(streak_in[v] + 1);
}

__global__ void k_gather(const float* __restrict__ cb,
                         const int* __restrict__ idx_i,
                         float* __restrict__ out) {
    size_t t  = (size_t)blockIdx.x * 256 + threadIdx.x;
    int    n  = (int)(t >> 7);
    int    d4 = (int)(t & 127);
    reinterpret_cast<float4*>(out)[t] =
        reinterpret_cast<const float4*>(cb + (size_t)idx_i[n] * DIM)[d4];
}

extern "C" void kernel_launch(void* const* d_in, const int* in_sizes, int n_in,
                              void* d_out, int out_size, void* d_ws, size_t ws_size,
                              hipStream_t stream) {
    const float* x      = (const float*)d_in[0];
    const float* cb     = (const float*)d_in[1];
    const int*   streak = (const int*)d_in[2];

    float* out       = (float*)d_out;
    float* out_embed = out;
    float* out_idx   = out + (size_t)N_ROWS * DIM;
    float* out_strk  = out_idx + N_ROWS;

    char* ws = (char*)d_ws;
    unsigned short* xhi  = (unsigned short*)(ws);                 // 16.8 MB
    unsigned short* cbhi = (unsigned short*)(ws + (32u << 20));   // 8.4 MB
    float* c2    = (float*)(ws + (48u << 20));                    // 32 KB
    int*   idx_i = (int*)(ws + (48u << 20) + (1u << 16));         // 64 KB
    int*   used  = (int*)(ws + (48u << 20) + (2u << 16));         // 32 KB
    float4* part = (float4*)(ws + (49u << 20));                   // 16.8 MB

    hipMemsetAsync(used, 0, VOCAB * sizeof(int), stream);
    k_split_hi<<<(N_ROWS * DIM / 4) / 256, 256, 0, stream>>>(x, xhi, N_ROWS * DIM / 4);
    k_split_cb<<<VOCAB / 4, 256, 0, stream>>>(cb, cbhi, c2);
    k_mfma_argmin<<<dim3(VOCAB / 128, N_ROWS / 256), 512, 0, stream>>>(
        xhi, cbhi, c2, part);
    k_select<<<N_ROWS / 4, 256, 0, stream>>>(part, x, cb, c2, out_idx, idx_i, used);
    k_streak<<<VOCAB / 256, 256, 0, stream>>>(streak, used, out_strk);
    k_gather<<<(N_ROWS * DIM / 4) / 256, 256, 0, stream>>>(cb, idx_i, out_embed);
}

// Round 13
// 288.153 us; speedup vs baseline: 2.1320x; 1.3190x over previous
//
#include <hip/hip_runtime.h>
#include <hip/hip_bf16.h>
#include <math.h>

// Problem: input (16,1024,512) f32, codebook (8192,512) f32
#define N_ROWS 16384
#define DIM    512
#define VOCAB  8192

typedef __attribute__((ext_vector_type(8))) short short8;
typedef __attribute__((ext_vector_type(4))) float f32x4;

__device__ inline unsigned short f2bf(float f) {      // RNE f32 -> bf16 bits
    unsigned u = __float_as_uint(f);
    u += 0x7fff + ((u >> 16) & 1);
    return (unsigned short)(u >> 16);
}

__device__ inline void gload16(const void* g, void* l) {
    __builtin_amdgcn_global_load_lds(
        (const __attribute__((address_space(1))) void*)g,
        (__attribute__((address_space(3))) void*)l, 16, 0, 0);
}

// ---------------------------------------------------------------------------
// fp32 -> bf16 for input x
// ---------------------------------------------------------------------------
__global__ void k_split_hi(const float* __restrict__ in, unsigned short* __restrict__ hi,
                           int n4) {
    int t = blockIdx.x * 256 + threadIdx.x;
    if (t >= n4) return;
    float4 v = reinterpret_cast<const float4*>(in)[t];
    ushort4 h;
    h.x = f2bf(v.x); h.y = f2bf(v.y); h.z = f2bf(v.z); h.w = f2bf(v.w);
    reinterpret_cast<ushort4*>(hi)[t] = h;
}

// ---------------------------------------------------------------------------
// codebook: fp32 -> bf16 AND c2[v] = sum(cb[v]^2) in one pass (validated)
// ---------------------------------------------------------------------------
__global__ void k_split_cb(const float* __restrict__ cb, unsigned short* __restrict__ hi,
                           float* __restrict__ c2) {
    int row  = blockIdx.x * 4 + (threadIdx.x >> 6);
    int lane = threadIdx.x & 63;
    const float4* p = reinterpret_cast<const float4*>(cb + (size_t)row * DIM);
    float4 a = p[lane * 2], b = p[lane * 2 + 1];
    float s = a.x*a.x + a.y*a.y + a.z*a.z + a.w*a.w
            + b.x*b.x + b.y*b.y + b.z*b.z + b.w*b.w;
    short8 h;
    h[0] = f2bf(a.x); h[1] = f2bf(a.y); h[2] = f2bf(a.z); h[3] = f2bf(a.w);
    h[4] = f2bf(b.x); h[5] = f2bf(b.y); h[6] = f2bf(b.z); h[7] = f2bf(b.w);
    *reinterpret_cast<short8*>(hi + (size_t)row * DIM + lane * 8) = h;
#pragma unroll
    for (int off = 32; off > 0; off >>= 1) s += __shfl_xor(s, off, 64);
    if (lane == 0) c2[row] = s;
}

// ---------------------------------------------------------------------------
// bf16 MFMA GEMM (K = 512) + fused per-tile top-2 argmin.
// EXACT r4-validated kernel (128x128 tile, BK=64, 256 thr = 4 waves of
// 32 rows x 128 cols, 32 KB single-buffer LDS + __syncthreads staging,
// rule-21 XOR swizzle, a[2]+b[8]-broadcast frags, direct register epilogue)
// with only: (1) K 1024 -> 512 (xhi only), (2) L2-blocked XCD grid map
// (validated r10): each XCD owns 16 row-tiles (A slab 2 MB, L2-resident),
// sweeps the 64 col-tiles inner (B tile refetched once per slab sweep).
// ---------------------------------------------------------------------------
__launch_bounds__(256, 2)
__global__ void k_mfma_argmin(const unsigned short* __restrict__ xhi,
                              const unsigned short* __restrict__ cbhi,
                              const float* __restrict__ c2,
                              float4* __restrict__ part) {
    __shared__ __align__(16) char As[16384];   // [128 rows][64 bf16], swizzled
    __shared__ __align__(16) char Bs[16384];
    const int tid  = threadIdx.x;
    const int w    = tid >> 6;
    const int lane = tid & 63;
    const int l15  = lane & 15;
    const int lg   = lane >> 4;

    // L2-blocked XCD map: 8192 blocks = 8 XCD x [64 bx x 16 by-slab]
    const int xcd = blockIdx.x & 7;
    const int i   = blockIdx.x >> 3;          // 0..1023
    const int by  = xcd * 16 + (i & 15);      // 0..127 (16-row-tile slab per XCD)
    const int bx  = i >> 4;                   // 0..63, inner sweep
    const int rowBase = by * 128;
    const int colBase = bx * 128;

    f32x4 acc[2][8];
#pragma unroll
    for (int mi = 0; mi < 2; ++mi)
#pragma unroll
        for (int nj = 0; nj < 8; ++nj) acc[mi][nj] = (f32x4)0.f;

    // staging (r2/r4-validated, 0 conflicts): chunk = 1024B = 8 rows of 128B;
    // lane -> (r = 8*chunk + lane>>3, slot = lane&7); source slot ^= row&7.
    const int r8     = lane >> 3;
    const int srcoff = ((lane & 7) ^ r8) << 4;

    for (int kt = 0; kt < 8; ++kt) {          // 8 K-tiles of 64 = K 512
        const int kb = kt << 7;               // byte offset within 1024B row
        if (kt) __syncthreads();
#pragma unroll
        for (int t = 0; t < 4; ++t) {
            int i2 = 4 * w + t;               // chunk index 0..15
            int r0 = 8 * i2;
            gload16((const char*)xhi + (size_t)(rowBase + r0 + r8) * 1024 + kb + srcoff,
                    As + 1024 * i2);
            gload16((const char*)cbhi + (size_t)(colBase + r0 + r8) * 1024 + kb + srcoff,
                    Bs + 1024 * i2);
        }
        __syncthreads();
#pragma unroll
        for (int kk = 0; kk < 2; ++kk) {
            const int ob = kk * 64 + lg * 16;
            short8 a[2], b[8];
#pragma unroll
            for (int mi = 0; mi < 2; ++mi) {
                int r = w * 32 + mi * 16 + l15;
                a[mi] = *(const short8*)(As + r * 128 + (ob ^ ((r & 7) << 4)));
            }
#pragma unroll
            for (int nj = 0; nj < 8; ++nj) {
                int r = nj * 16 + l15;
                b[nj] = *(const short8*)(Bs + r * 128 + (ob ^ ((r & 7) << 4)));
            }
#pragma unroll
            for (int mi = 0; mi < 2; ++mi)
#pragma unroll
                for (int nj = 0; nj < 8; ++nj)
                    acc[mi][nj] = __builtin_amdgcn_mfma_f32_16x16x32_bf16(
                        a[mi], b[nj], acc[mi][nj], 0, 0, 0);
        }
    }

    // Epilogue (r2/r4-validated): score = c2[v] - 2*dot; per-row top-2 over
    // this block's 128 cols. C layout (m89): col = lane&15, row = 4*(lane>>4)+reg.
    float c2v[8];
#pragma unroll
    for (int nj = 0; nj < 8; ++nj) c2v[nj] = c2[colBase + nj * 16 + l15];

#pragma unroll
    for (int mi = 0; mi < 2; ++mi) {
#pragma unroll
        for (int reg = 0; reg < 4; ++reg) {
            float s1 = INFINITY, s2 = INFINITY;
            int   i1 = 0x7fffffff, i2 = 0x7fffffff;
#pragma unroll
            for (int nj = 0; nj < 8; ++nj) {
                float s = fmaf(-2.f, acc[mi][nj][reg], c2v[nj]);
                int   v = colBase + nj * 16 + l15;
                if (s < s1 || (s == s1 && v < i1)) { s2 = s1; i2 = i1; s1 = s; i1 = v; }
                else if (s < s2 || (s == s2 && v < i2)) { s2 = s; i2 = v; }
            }
#pragma unroll
            for (int off = 1; off < 16; off <<= 1) {   // butterfly over 16 col-lanes
                float t1 = __shfl_xor(s1, off, 64); int j1 = __shfl_xor(i1, off, 64);
                float t2 = __shfl_xor(s2, off, 64); int j2 = __shfl_xor(i2, off, 64);
                bool bfirst = (t1 < s1) || (t1 == s1 && j1 < i1);
                if (bfirst) {
                    float n2s; int n2i;
                    if (s1 < t2 || (s1 == t2 && i1 < j2)) { n2s = s1; n2i = i1; }
                    else                                   { n2s = t2; n2i = j2; }
                    s1 = t1; i1 = j1; s2 = n2s; i2 = n2i;
                } else {
                    if (t1 < s2 || (t1 == s2 && j1 < i2)) { s2 = t1; i2 = j1; }
                }
            }
            if (l15 == 0) {
                int row = rowBase + w * 32 + mi * 16 + 4 * lg + reg;
                part[(size_t)row * 64 + bx] =
                    make_float4(s1, __int_as_float(i1), s2, __int_as_float(i2));
            }
        }
    }
}

// ---------------------------------------------------------------------------
// Per-row final: approx global min over 64 per-128-col top2s; exact fp32
// rescore of all candidates within min+1.0 (>14 sigma of bf16 approx error);
// lexicographic (score, idx) min == reference argmin semantics.
// ---------------------------------------------------------------------------
__global__ void k_select(const float4* __restrict__ part,
                         const float* __restrict__ x,
                         const float* __restrict__ cb,
                         const float* __restrict__ c2,
                         float* __restrict__ out_idx_f,
                         int* __restrict__ idx_i,
                         int* __restrict__ used) {
    int wv   = threadIdx.x >> 6;
    int lane = threadIdx.x & 63;
    int row  = blockIdx.x * 4 + wv;
    float4 p = part[(size_t)row * 64 + lane];
    float s1 = p.x; int i1 = __float_as_int(p.y);
    float s2 = p.z; int i2 = __float_as_int(p.w);
    float gm = s1;
#pragma unroll
    for (int off = 1; off < 64; off <<= 1) gm = fminf(gm, __shfl_xor(gm, off, 64));
    float thresh = gm + 1.0f;
    unsigned long long m1 = __ballot(s1 <= thresh);
    unsigned long long m2 = __ballot(s2 <= thresh);
    float be = INFINITY; int bi = 0x7fffffff;
    const float4* xr = reinterpret_cast<const float4*>(x + (size_t)row * DIM);
    while (m1 | m2) {
        int vi;
        if (m1) { int t = __ffsll(m1) - 1; m1 &= m1 - 1; vi = __shfl(i1, t); }
        else    { int t = __ffsll(m2) - 1; m2 &= m2 - 1; vi = __shfl(i2, t); }
        const float4* cr = reinterpret_cast<const float4*>(cb + (size_t)vi * DIM);
        float d = 0.f;
#pragma unroll
        for (int q = 0; q < 2; ++q) {
            float4 a = xr[q * 64 + lane];
            float4 b = cr[q * 64 + lane];
            d += a.x * b.x + a.y * b.y + a.z * b.z + a.w * b.w;
        }
#pragma unroll
        for (int off = 1; off < 64; off <<= 1) d += __shfl_xor(d, off, 64);
        float se = c2[vi] - 2.f * d;
        if (se < be || (se == be && vi < bi)) { be = se; bi = vi; }
    }
    if (lane == 0) {
        out_idx_f[row] = (float)bi;
        idx_i[row]     = bi;
        used[bi]       = 1;
    }
}

__global__ void k_streak(const int* __restrict__ streak_in,
                         const int* __restrict__ used,
                         float* __restrict__ out) {
    int v = blockIdx.x * 256 + threadIdx.x;
    if (v < VOCAB) out[v] = used[v] ? 0.f : (float)(streak_in[v] + 1);
}

__global__ void k_gather(const float* __restrict__ cb,
                         const int* __restrict__ idx_i,
                         float* __restrict__ out) {
    size_t t  = (size_t)blockIdx.x * 256 + threadIdx.x;
    int    n  = (int)(t >> 7);
    int    d4 = (int)(t & 127);
    reinterpret_cast<float4*>(out)[t] =
        reinterpret_cast<const float4*>(cb + (size_t)idx_i[n] * DIM)[d4];
}

extern "C" void kernel_launch(void* const* d_in, const int* in_sizes, int n_in,
                              void* d_out, int out_size, void* d_ws, size_t ws_size,
                              hipStream_t stream) {
    const float* x      = (const float*)d_in[0];
    const float* cb     = (const float*)d_in[1];
    const int*   streak = (const int*)d_in[2];

    float* out       = (float*)d_out;
    float* out_embed = out;
    float* out_idx   = out + (size_t)N_ROWS * DIM;
    float* out_strk  = out_idx + N_ROWS;

    char* ws = (char*)d_ws;
    unsigned short* xhi  = (unsigned short*)(ws);                 // 16.8 MB
    unsigned short* cbhi = (unsigned short*)(ws + (32u << 20));   // 8.4 MB
    float* c2    = (float*)(ws + (48u << 20));                    // 32 KB
    int*   idx_i = (int*)(ws + (48u << 20) + (1u << 16));         // 64 KB
    int*   used  = (int*)(ws + (48u << 20) + (2u << 16));         // 32 KB
    float4* part = (float4*)(ws + (49u << 20));                   // 16.8 MB

    hipMemsetAsync(used, 0, VOCAB * sizeof(int), stream);
    k_split_hi<<<(N_ROWS * DIM / 4) / 256, 256, 0, stream>>>(x, xhi, N_ROWS * DIM / 4);
    k_split_cb<<<VOCAB / 4, 256, 0, stream>>>(cb, cbhi, c2);
    k_mfma_argmin<<<8192, 256, 0, stream>>>(xhi, cbhi, c2, part);
    k_select<<<N_ROWS / 4, 256, 0, stream>>>(part, x, cb, c2, out_idx, idx_i, used);
    k_streak<<<VOCAB / 256, 256, 0, stream>>>(streak, used, out_strk);
    k_gather<<<(N_ROWS * DIM / 4) / 256, 256, 0, stream>>>(cb, idx_i, out_embed);
}

// Round 14
// 225.944 us; speedup vs baseline: 2.7190x; 1.2753x over previous
//
#include <hip/hip_runtime.h>
#include <hip/hip_bf16.h>
#include <math.h>

// Problem: input (16,1024,512) f32, codebook (8192,512) f32
#define N_ROWS 16384
#define DIM    512
#define VOCAB  8192

typedef __attribute__((ext_vector_type(4))) float f32x4;

__device__ inline void gload16(const void* g, void* l) {
    __builtin_amdgcn_global_load_lds(
        (const __attribute__((address_space(1))) void*)g,
        (__attribute__((address_space(3))) void*)l, 16, 0, 0);
}

// pack 4 floats -> 4 fp8(e4m3) bytes via HW cvt
__device__ inline int pk4_fp8(float4 v) {
    int p = __builtin_amdgcn_cvt_pk_fp8_f32(v.x, v.y, 0, false);
    return  __builtin_amdgcn_cvt_pk_fp8_f32(v.z, v.w, p, true);
}

// ---------------------------------------------------------------------------
// fp32 -> fp8 e4m3 for input x (8 elems/thread)
// ---------------------------------------------------------------------------
__global__ void k_split_x(const float* __restrict__ in, unsigned char* __restrict__ q,
                          int n8) {
    int t = blockIdx.x * 256 + threadIdx.x;
    if (t >= n8) return;
    const float4* p = reinterpret_cast<const float4*>(in) + 2 * (size_t)t;
    int2 r = make_int2(pk4_fp8(p[0]), pk4_fp8(p[1]));
    reinterpret_cast<int2*>(q)[t] = r;
}

// ---------------------------------------------------------------------------
// codebook: fp32 -> fp8 e4m3 AND exact fp32 c2[v] in one pass.
// One wave per row (512 floats = 8/lane), 4 waves/block.
// ---------------------------------------------------------------------------
__global__ void k_split_cb(const float* __restrict__ cb, unsigned char* __restrict__ q,
                           float* __restrict__ c2) {
    int row  = blockIdx.x * 4 + (threadIdx.x >> 6);
    int lane = threadIdx.x & 63;
    const float4* p = reinterpret_cast<const float4*>(cb + (size_t)row * DIM);
    float4 a = p[lane * 2], b = p[lane * 2 + 1];
    float s = a.x*a.x + a.y*a.y + a.z*a.z + a.w*a.w
            + b.x*b.x + b.y*b.y + b.z*b.z + b.w*b.w;
    reinterpret_cast<int2*>(q + (size_t)row * DIM)[lane] =
        make_int2(pk4_fp8(a), pk4_fp8(b));
#pragma unroll
    for (int off = 32; off > 0; off >>= 1) s += __shfl_xor(s, off, 64);
    if (lane == 0) c2[row] = s;
}

// ---------------------------------------------------------------------------
// fp8 MFMA GEMM (K = 512) + fused per-tile top-2 argmin.
// r13-validated geometry, fp8 edition: one K-tile = 128 K-elems = the SAME
// 128 B LDS row as r13's bf16-64 tile -> identical 1024B-chunk staging map,
// identical ^(r&7) 16B-slot swizzle (rule 21), identical L2-blocked XCD grid,
// identical epilogue (C/D layout is dtype-independent). K-steps 8 -> 4,
// staged bytes halved, 64 MFMA/wave/step (mfma_f32_16x16x32_fp8_fp8, b64
// fragments: 8 fp8 k-elems per lane-group).
// ---------------------------------------------------------------------------
__launch_bounds__(256, 2)
__global__ void k_mfma_argmin(const unsigned char* __restrict__ xq,
                              const unsigned char* __restrict__ cbq,
                              const float* __restrict__ c2,
                              float4* __restrict__ part) {
    __shared__ __align__(16) char As[16384];   // [128 rows][128 fp8], swizzled
    __shared__ __align__(16) char Bs[16384];
    const int tid  = threadIdx.x;
    const int w    = tid >> 6;
    const int lane = tid & 63;
    const int l15  = lane & 15;
    const int lg   = lane >> 4;

    // L2-blocked XCD map (r13-validated): 8192 = 8 XCD x [64 bx x 16 by-slab]
    const int xcd = blockIdx.x & 7;
    const int i   = blockIdx.x >> 3;
    const int by  = xcd * 16 + (i & 15);
    const int bx  = i >> 4;
    const int rowBase = by * 128;
    const int colBase = bx * 128;

    f32x4 acc[2][8];
#pragma unroll
    for (int mi = 0; mi < 2; ++mi)
#pragma unroll
        for (int nj = 0; nj < 8; ++nj) acc[mi][nj] = (f32x4)0.f;

    // staging (r13 scheme): chunk = 1024B = 8 rows of 128B;
    // lane -> (r = 8*chunk + lane>>3, slot = lane&7); source slot ^= row&7.
    const int r8     = lane >> 3;
    const int srcoff = ((lane & 7) ^ r8) << 4;

    for (int kt = 0; kt < 4; ++kt) {          // 4 K-tiles of 128 = K 512
        const int kb = kt << 7;               // byte offset within 512B row
        if (kt) __syncthreads();
#pragma unroll
        for (int t = 0; t < 4; ++t) {
            int i2 = 4 * w + t;               // chunk index 0..15
            int r0 = 8 * i2;
            gload16(xq  + (size_t)(rowBase + r0 + r8) * 512 + kb + srcoff,
                    As + 1024 * i2);
            gload16(cbq + (size_t)(colBase + r0 + r8) * 512 + kb + srcoff,
                    Bs + 1024 * i2);
        }
        __syncthreads();
#pragma unroll
        for (int s = 0; s < 4; ++s) {         // 4 x K=32 MFMA sub-steps
            const int s16 = s * 2 + (lg >> 1);   // 16B slot of the 8B frag
            const int rem = (lg & 1) * 8;
            long a[2], b[8];
#pragma unroll
            for (int mi = 0; mi < 2; ++mi) {
                int r = w * 32 + mi * 16 + l15;
                a[mi] = *(const long*)(As + r * 128 + ((s16 ^ (r & 7)) << 4) + rem);
            }
#pragma unroll
            for (int nj = 0; nj < 8; ++nj) {
                int r = nj * 16 + l15;
                b[nj] = *(const long*)(Bs + r * 128 + ((s16 ^ (r & 7)) << 4) + rem);
            }
#pragma unroll
            for (int mi = 0; mi < 2; ++mi)
#pragma unroll
                for (int nj = 0; nj < 8; ++nj)
                    acc[mi][nj] = __builtin_amdgcn_mfma_f32_16x16x32_fp8_fp8(
                        a[mi], b[nj], acc[mi][nj], 0, 0, 0);
        }
    }

    // Epilogue (r13-validated): score = c2[v] - 2*dot; per-row top-2 over
    // this block's 128 cols. C layout: col = lane&15, row = 4*(lane>>4)+reg.
    float c2v[8];
#pragma unroll
    for (int nj = 0; nj < 8; ++nj) c2v[nj] = c2[colBase + nj * 16 + l15];

#pragma unroll
    for (int mi = 0; mi < 2; ++mi) {
#pragma unroll
        for (int reg = 0; reg < 4; ++reg) {
            float s1 = INFINITY, s2 = INFINITY;
            int   i1 = 0x7fffffff, i2 = 0x7fffffff;
#pragma unroll
            for (int nj = 0; nj < 8; ++nj) {
                float s = fmaf(-2.f, acc[mi][nj][reg], c2v[nj]);
                int   v = colBase + nj * 16 + l15;
                if (s < s1 || (s == s1 && v < i1)) { s2 = s1; i2 = i1; s1 = s; i1 = v; }
                else if (s < s2 || (s == s2 && v < i2)) { s2 = s; i2 = v; }
            }
#pragma unroll
            for (int off = 1; off < 16; off <<= 1) {   // butterfly over 16 col-lanes
                float t1 = __shfl_xor(s1, off, 64); int j1 = __shfl_xor(i1, off, 64);
                float t2 = __shfl_xor(s2, off, 64); int j2 = __shfl_xor(i2, off, 64);
                bool bfirst = (t1 < s1) || (t1 == s1 && j1 < i1);
                if (bfirst) {
                    float n2s; int n2i;
                    if (s1 < t2 || (s1 == t2 && i1 < j2)) { n2s = s1; n2i = i1; }
                    else                                   { n2s = t2; n2i = j2; }
                    s1 = t1; i1 = j1; s2 = n2s; i2 = n2i;
                } else {
                    if (t1 < s2 || (t1 == s2 && j1 < i2)) { s2 = t1; i2 = j1; }
                }
            }
            if (l15 == 0) {
                int row = rowBase + w * 32 + mi * 16 + 4 * lg + reg;
                part[(size_t)row * 64 + bx] =
                    make_float4(s1, __int_as_float(i1), s2, __int_as_float(i2));
            }
        }
    }
}

// ---------------------------------------------------------------------------
// Per-row final: approx global min over 64 per-128-col top2s; exact fp32
// rescore of all candidates within min+16.0 (~7 sigma of fp8 approx error);
// lexicographic (score, idx) min == reference argmin semantics.
// ---------------------------------------------------------------------------
__global__ void k_select(const float4* __restrict__ part,
                         const float* __restrict__ x,
                         const float* __restrict__ cb,
                         const float* __restrict__ c2,
                         float* __restrict__ out_idx_f,
                         int* __restrict__ idx_i,
                         int* __restrict__ used) {
    int wv   = threadIdx.x >> 6;
    int lane = threadIdx.x & 63;
    int row  = blockIdx.x * 4 + wv;
    float4 p = part[(size_t)row * 64 + lane];
    float s1 = p.x; int i1 = __float_as_int(p.y);
    float s2 = p.z; int i2 = __float_as_int(p.w);
    float gm = s1;
#pragma unroll
    for (int off = 1; off < 64; off <<= 1) gm = fminf(gm, __shfl_xor(gm, off, 64));
    float thresh = gm + 16.0f;
    unsigned long long m1 = __ballot(s1 <= thresh);
    unsigned long long m2 = __ballot(s2 <= thresh);
    float be = INFINITY; int bi = 0x7fffffff;
    const float4* xr = reinterpret_cast<const float4*>(x + (size_t)row * DIM);
    while (m1 | m2) {
        int vi;
        if (m1) { int t = __ffsll(m1) - 1; m1 &= m1 - 1; vi = __shfl(i1, t); }
        else    { int t = __ffsll(m2) - 1; m2 &= m2 - 1; vi = __shfl(i2, t); }
        const float4* cr = reinterpret_cast<const float4*>(cb + (size_t)vi * DIM);
        float d = 0.f;
#pragma unroll
        for (int q = 0; q < 2; ++q) {
            float4 a = xr[q * 64 + lane];
            float4 b = cr[q * 64 + lane];
            d += a.x * b.x + a.y * b.y + a.z * b.z + a.w * b.w;
        }
#pragma unroll
        for (int off = 1; off < 64; off <<= 1) d += __shfl_xor(d, off, 64);
        float se = c2[vi] - 2.f * d;
        if (se < be || (se == be && vi < bi)) { be = se; bi = vi; }
    }
    if (lane == 0) {
        out_idx_f[row] = (float)bi;
        idx_i[row]     = bi;
        used[bi]       = 1;
    }
}

__global__ void k_streak(const int* __restrict__ streak_in,
                         const int* __restrict__ used,
                         float* __restrict__ out) {
    int v = blockIdx.x * 256 + threadIdx.x;
    if (v < VOCAB) out[v] = used[v] ? 0.f : (float)(streak_in[v] + 1);
}

__global__ void k_gather(const float* __restrict__ cb,
                         const int* __restrict__ idx_i,
                         float* __restrict__ out) {
    size_t t  = (size_t)blockIdx.x * 256 + threadIdx.x;
    int    n  = (int)(t >> 7);
    int    d4 = (int)(t & 127);
    reinterpret_cast<float4*>(out)[t] =
        reinterpret_cast<const float4*>(cb + (size_t)idx_i[n] * DIM)[d4];
}

extern "C" void kernel_launch(void* const* d_in, const int* in_sizes, int n_in,
                              void* d_out, int out_size, void* d_ws, size_t ws_size,
                              hipStream_t stream) {
    const float* x      = (const float*)d_in[0];
    const float* cb     = (const float*)d_in[1];
    const int*   streak = (const int*)d_in[2];

    float* out       = (float*)d_out;
    float* out_embed = out;
    float* out_idx   = out + (size_t)N_ROWS * DIM;
    float* out_strk  = out_idx + N_ROWS;

    char* ws = (char*)d_ws;
    unsigned char* xq  = (unsigned char*)(ws);                  // 8.4 MB
    unsigned char* cbq = (unsigned char*)(ws + (16u << 20));    // 4.2 MB
    float* c2    = (float*)(ws + (48u << 20));                  // 32 KB
    int*   idx_i = (int*)(ws + (48u << 20) + (1u << 16));       // 64 KB
    int*   used  = (int*)(ws + (48u << 20) + (2u << 16));       // 32 KB
    float4* part = (float4*)(ws + (49u << 20));                 // 16.8 MB

    hipMemsetAsync(used, 0, VOCAB * sizeof(int), stream);
    k_split_x<<<(N_ROWS * DIM / 8) / 256, 256, 0, stream>>>(x, xq, N_ROWS * DIM / 8);
    k_split_cb<<<VOCAB / 4, 256, 0, stream>>>(cb, cbq, c2);
    k_mfma_argmin<<<8192, 256, 0, stream>>>(xq, cbq, c2, part);
    k_select<<<N_ROWS / 4, 256, 0, stream>>>(part, x, cb, c2, out_idx, idx_i, used);
    k_streak<<<VOCAB / 256, 256, 0, stream>>>(streak, used, out_strk);
    k_gather<<<(N_ROWS * DIM / 4) / 256, 256, 0, stream>>>(cb, idx_i, out_embed);
}